// Round 2
// baseline (143.935 us; speedup 1.0000x reference)
//
#include <hip/hip_runtime.h>

#define GAT_H 12
#define GAT_N 4096
#define GAT_F 64
#define LOG2E 1.4426950408889634f

// ---------------------------------------------------------------------------
// Algebra: with q = log2e*(x_i*s_h + x_j*d_h),
//   exp2(lrelu(q)) = max(exp2(q), exp2(0.2q))     [lrelu(q)=max(q,0.2q), exp2 monotone]
//                  = B1(i,h) * max(E1(j,h), rho(i,h)*E2(j,h))
// B1 depends only on (i,h) -> cancels in softmax.  Tables (device-global,
// NOT workspace -- ws_size is unknown and an OOB table write crashes the box):
//   g_tab[h][j] = (exp2(log2e*d_h*x_j), exp2(0.2*log2e*d_h*x_j))   [384 KB, L2-resident]
//   rho = exp2(-0.8*log2e*x_i*s_h)                                 [48 scalars/block]
// Inner loop per (i,j,h): mul + max + 2 fma. NO transcendentals.
// ---------------------------------------------------------------------------

__device__ float2 g_tab[GAT_H * GAT_N];   // 384 KB static device memory
__device__ float  g_sd[2 * GAT_H + 1];    // s[12], d[12], mean(x)

__global__ __launch_bounds__(256) void gat_prep(const float* __restrict__ W,
                                                const float* __restrict__ a,
                                                const float* __restrict__ x) {
    const int b    = blockIdx.x;
    const int tid  = threadIdx.x;
    const int lane = tid & 63;
    const int wave = tid >> 6;

    if (b < GAT_H) {                       // s_h, d_h (wave 0 only)
        if (wave == 0) {
            const float wf = W[b * GAT_F + lane];
            float ps = wf * a[b * 2 * GAT_F + lane];
            float pd = wf * a[b * 2 * GAT_F + GAT_F + lane];
            #pragma unroll
            for (int off = 32; off > 0; off >>= 1) {
                ps += __shfl_xor(ps, off, 64);
                pd += __shfl_xor(pd, off, 64);
            }
            if (lane == 0) { g_sd[b] = ps; g_sd[GAT_H + b] = pd; }
        }
        return;
    }
    if (b == GAT_H) {                      // mean(x) fallback (wave 0 only)
        if (wave == 0) {
            float s = 0.0f;
            #pragma unroll
            for (int j = 0; j < GAT_N / 64; ++j) s += x[j * 64 + lane];
            #pragma unroll
            for (int off = 32; off > 0; off >>= 1) s += __shfl_xor(s, off, 64);
            if (lane == 0) g_sd[2 * GAT_H] = s * (1.0f / GAT_N);
        }
        return;
    }

    // Table blocks: bt in [0,48): h = bt>>2, 1024-wide j-chunk = bt&3.
    // Each wave recomputes d_h locally (no cross-block dependency).
    const int bt    = b - (GAT_H + 1);
    const int h     = bt >> 2;
    const int chunk = bt & 3;
    const float wf  = W[h * GAT_F + lane];
    float pd = wf * a[h * 2 * GAT_F + GAT_F + lane];
    #pragma unroll
    for (int off = 32; off > 0; off >>= 1) pd += __shfl_xor(pd, off, 64);
    const float dl = pd * LOG2E;
    #pragma unroll
    for (int k = 0; k < 4; ++k) {
        const int j   = chunk * 1024 + k * 256 + tid;
        const float t = dl * x[j];
        g_tab[h * GAT_N + j] = make_float2(__builtin_amdgcn_exp2f(t),
                                           __builtin_amdgcn_exp2f(0.2f * t));
    }
}

// Main: 4 rows/block, 4 waves = (h-group 0/1 of 6 heads) x (j-half 0/1).
// Per element per wave: 4 adj dwords + 6 table float2 + 1 LDS x read,
// ~12 mask VALU + 96 triple VALU (mul/max/fma/fma per (h,row)).
__global__ __launch_bounds__(256, 4) void gat_main(const float* __restrict__ x,
                                                   const int* __restrict__ adj,
                                                   const float* __restrict__ W,
                                                   float* __restrict__ out) {
    __shared__ float xs[GAT_N];
    __shared__ float rho_s[4][16];
    __shared__ float part[2][2][4][6][2];   // [jh][hg][row][hh][den,num]
    __shared__ float cbuf[4][GAT_H];

    const int tid  = threadIdx.x;
    const int row0 = blockIdx.x * 4;

    #pragma unroll
    for (int it = 0; it < GAT_N / (256 * 4); ++it)
        ((float4*)xs)[it * 256 + tid] = ((const float4*)x)[it * 256 + tid];
    if (tid < 64) {
        const int r = tid >> 4, hh = tid & 15;
        if (hh < GAT_H)
            rho_s[r][hh] =
                __builtin_amdgcn_exp2f(-0.8f * LOG2E * x[row0 + r] * g_sd[hh]);
    }
    __syncthreads();

    const int lane  = tid & 63;
    const int wave  = tid >> 6;
    const int hg    = wave >> 1;
    const int jh    = wave & 1;
    const int hbase = hg * 6;
    const int jb    = jh * 2048 + lane;

    // rho is wave-uniform -> pin to SGPRs so the per-triple mul reads SGPR.
    float rho[4][6];
    #pragma unroll
    for (int r = 0; r < 4; ++r)
        #pragma unroll
        for (int hh = 0; hh < 6; ++hh)
            rho[r][hh] = __uint_as_float(__builtin_amdgcn_readfirstlane(
                __float_as_uint(rho_s[r][hbase + hh])));

    float den[4][6], num[4][6];
    #pragma unroll
    for (int r = 0; r < 4; ++r)
        #pragma unroll
        for (int hh = 0; hh < 6; ++hh) { den[r][hh] = 0.0f; num[r][hh] = 0.0f; }

    const int*    __restrict__ adp = adj + (size_t)row0 * GAT_N + jb;
    const float2* __restrict__ tb  = g_tab + hbase * GAT_N + jb;

    int    a_c[4];
    float2 E_c[6];
    float  x_c;
    #pragma unroll
    for (int r = 0; r < 4; ++r)  a_c[r]  = adp[r * GAT_N];
    #pragma unroll
    for (int hh = 0; hh < 6; ++hh) E_c[hh] = tb[hh * GAT_N];
    x_c = xs[jb];

    #pragma unroll 2
    for (int e = 0; e < 32; ++e) {
        const int eo = (e < 31 ? e + 1 : 31) * 64;      // clamped prefetch
        int    a_n[4];
        float2 E_n[6];
        #pragma unroll
        for (int r = 0; r < 4; ++r)   a_n[r]  = adp[r * GAT_N + eo];
        #pragma unroll
        for (int hh = 0; hh < 6; ++hh) E_n[hh] = tb[hh * GAT_N + eo];
        const float x_n = xs[jb + eo];

        float m[4], mxj[4];
        #pragma unroll
        for (int r = 0; r < 4; ++r) {
            const bool nb = a_c[r] > 0;
            m[r]   = nb ? 1.0f : 0.0f;
            mxj[r] = nb ? x_c  : 0.0f;
        }
        #pragma unroll
        for (int hh = 0; hh < 6; ++hh) {
            const float e1 = E_c[hh].x, e2 = E_c[hh].y;
            #pragma unroll
            for (int r = 0; r < 4; ++r) {
                const float p = fmaxf(e1, rho[r][hh] * e2);
                den[r][hh] = fmaf(p, m[r],   den[r][hh]);
                num[r][hh] = fmaf(p, mxj[r], num[r][hh]);
            }
        }
        #pragma unroll
        for (int r = 0; r < 4; ++r)   a_c[r]  = a_n[r];
        #pragma unroll
        for (int hh = 0; hh < 6; ++hh) E_c[hh] = E_n[hh];
        x_c = x_n;
    }

    #pragma unroll
    for (int r = 0; r < 4; ++r) {
        #pragma unroll
        for (int hh = 0; hh < 6; ++hh) {
            float d = den[r][hh], n = num[r][hh];
            #pragma unroll
            for (int off = 32; off > 0; off >>= 1) {
                d += __shfl_xor(d, off, 64);
                n += __shfl_xor(n, off, 64);
            }
            if (lane == 0) {
                part[jh][hg][r][hh][0] = d;
                part[jh][hg][r][hh][1] = n;
            }
        }
    }
    __syncthreads();

    if (tid < 64) {
        const int r = tid >> 4, h = tid & 15;
        if (h < GAT_H) {
            const int g  = (h >= 6) ? 1 : 0;
            const int hh = h - 6 * g;
            const float dsum = part[0][g][r][hh][0] + part[1][g][r][hh][0];
            const float nsum = part[0][g][r][hh][1] + part[1][g][r][hh][1];
            cbuf[r][h] = dsum > 0.0f ? nsum / dsum : g_sd[2 * GAT_H];
        }
    }
    __syncthreads();

    #pragma unroll
    for (int r = 0; r < 4; ++r) {
        const size_t base = (size_t)(row0 + r) * (GAT_H * GAT_F);
        #pragma unroll
        for (int k = 0; k < 3; ++k) {
            const int pos = k * 256 + tid;
            out[base + pos] = cbuf[r][pos >> 6] * W[pos];
        }
    }
}

extern "C" void kernel_launch(void* const* d_in, const int* in_sizes, int n_in,
                              void* d_out, int out_size, void* d_ws, size_t ws_size,
                              hipStream_t stream) {
    const float* x   = (const float*)d_in[0];
    const int*   adj = (const int*)d_in[1];
    const float* W   = (const float*)d_in[2];
    const float* a   = (const float*)d_in[3];
    float* out = (float*)d_out;
    (void)d_ws; (void)ws_size;   // all scratch is static __device__ memory

    gat_prep<<<GAT_H + 1 + 48, 256, 0, stream>>>(W, a, x);
    gat_main<<<GAT_N / 4, 256, 0, stream>>>(x, adj, W, out);
}